// Round 12
// baseline (325.255 us; speedup 1.0000x reference)
//
#include <hip/hip_runtime.h>

static constexpr int DIN = 128;
static constexpr int HID = 64;
static constexpr int BIN_SHIFT = 8;    // 256 nodes per bin
static constexpr int CHUNK = 1024;     // r9 (neutral, kept)

typedef short bf16x8 __attribute__((ext_vector_type(8)));
typedef float f32x4  __attribute__((ext_vector_type(4)));
typedef _Float16 half4 __attribute__((ext_vector_type(4)));
typedef _Float16 half8 __attribute__((ext_vector_type(8)));

// bf16 helpers (manual RNE, no header dependence)
__device__ __forceinline__ short f2bf(float f) {
    unsigned u = __float_as_uint(f);
    unsigned r = (u + 0x7fff + ((u >> 16) & 1)) >> 16;
    return (short)r;
}
__device__ __forceinline__ float bf2f(short s) {
    return __uint_as_float(((unsigned)(unsigned short)s) << 16);
}

// ===========================================================================
// Two-level CSR build (proven r6/r8): bins of 256 nodes localize all scatter.
// pairs packed as (dstLocal<<24)|src (src < 2^17, dstLocal 8b).
// ===========================================================================
__global__ __launch_bounds__(256) void binhist_kernel(
    const int* __restrict__ dstA, const int* __restrict__ dstB,
    int* __restrict__ binCnt, int nE, int gA, int nbA, int nbT)
{
    __shared__ int c[1024];
    for (int b = threadIdx.x; b < 1024; b += 256) c[b] = 0;
    __syncthreads();
    const int blk = blockIdx.x;
    const bool isA = blk < gA;
    const int* dst = isA ? dstA : dstB;
    const int off  = isA ? 0 : nbA;
    const int i0   = (isA ? blk : blk - gA) * CHUNK;
    #pragma unroll 4
    for (int k = 0; k < CHUNK / 256; ++k) {
        int i = i0 + k * 256 + threadIdx.x;
        if (i < nE) atomicAdd(&c[off + (dst[i] >> BIN_SHIFT)], 1);
    }
    __syncthreads();
    for (int b = threadIdx.x; b < nbT; b += 256) {
        int v = c[b];
        if (v) atomicAdd(&binCnt[b], v);
    }
}

__global__ __launch_bounds__(1024) void binscan_kernel(
    const int* __restrict__ binCnt, int* __restrict__ binBase,
    int* __restrict__ binCur, int nbT)
{
    __shared__ int s[1024];
    int v = (threadIdx.x < nbT) ? binCnt[threadIdx.x] : 0;
    s[threadIdx.x] = v;
    __syncthreads();
    for (int o = 1; o < 1024; o <<= 1) {
        int t = (threadIdx.x >= o) ? s[threadIdx.x - o] : 0;
        __syncthreads();
        s[threadIdx.x] += t;
        __syncthreads();
    }
    if (threadIdx.x < nbT) {
        binBase[threadIdx.x] = s[threadIdx.x] - v;
        binCur[threadIdx.x]  = s[threadIdx.x] - v;
    }
}

__global__ __launch_bounds__(256) void binplaceA_kernel(
    const int* __restrict__ srcA, const int* __restrict__ dstA,
    const int* __restrict__ srcB, const int* __restrict__ dstB,
    int* __restrict__ binCur, unsigned int* __restrict__ pairs,
    int nE, int gA, int nbA, int nbT)
{
    __shared__ int cnt[1024];
    __shared__ int base[1024];
    for (int b = threadIdx.x; b < 1024; b += 256) cnt[b] = 0;
    __syncthreads();
    const int blk = blockIdx.x;
    const bool isA = blk < gA;
    const int* src = isA ? srcA : srcB;
    const int* dst = isA ? dstA : dstB;
    const int off  = isA ? 0 : nbA;
    const int i0   = (isA ? blk : blk - gA) * CHUNK;
    #pragma unroll 4
    for (int k = 0; k < CHUNK / 256; ++k) {
        int i = i0 + k * 256 + threadIdx.x;
        if (i < nE) atomicAdd(&cnt[off + (dst[i] >> BIN_SHIFT)], 1);
    }
    __syncthreads();
    for (int b = threadIdx.x; b < nbT; b += 256) {
        int v = cnt[b];
        base[b] = v ? atomicAdd(&binCur[b], v) : 0;
        cnt[b] = 0;
    }
    __syncthreads();
    #pragma unroll 4
    for (int k = 0; k < CHUNK / 256; ++k) {
        int i = i0 + k * 256 + threadIdx.x;
        if (i < nE) {
            int d  = dst[i];
            int bn = off + (d >> BIN_SHIFT);
            int p  = base[bn] + atomicAdd(&cnt[bn], 1);
            pairs[p] = ((unsigned)(d & 255) << 24) | (unsigned)src[i];
        }
    }
}

__global__ __launch_bounds__(256) void binplaceB_kernel(
    const unsigned int* __restrict__ pairs,
    const int* __restrict__ binBase, const int* __restrict__ binCnt,
    int* __restrict__ startsA, int* __restrict__ cntA, int* __restrict__ colA, int NA,
    int* __restrict__ startsB, int* __restrict__ cntB, int* __restrict__ colB, int NB,
    int nbA, int nE)
{
    __shared__ int lc[256];
    __shared__ int pr[256];
    const int b    = blockIdx.x;
    const bool isA = b < nbA;
    int* starts = isA ? startsA : startsB;
    int* cntN   = isA ? cntA : cntB;
    int* col    = isA ? colA : colB;
    const int N     = isA ? NA : NB;
    const int node0 = (isA ? b : b - nbA) << BIN_SHIFT;
    const int e0 = binBase[b];
    const int ec = binCnt[b];
    const int colBase = isA ? e0 : e0 - nE;

    lc[threadIdx.x] = 0;
    __syncthreads();
    for (int e = threadIdx.x; e < ec; e += 256)
        atomicAdd(&lc[pairs[e0 + e] >> 24], 1);
    __syncthreads();
    const int v = lc[threadIdx.x];
    pr[threadIdx.x] = v;
    __syncthreads();
    for (int o = 1; o < 256; o <<= 1) {
        int t = (threadIdx.x >= o) ? pr[threadIdx.x - o] : 0;
        __syncthreads();
        pr[threadIdx.x] += t;
        __syncthreads();
    }
    const int myStart = colBase + pr[threadIdx.x] - v;
    const int n = node0 + threadIdx.x;
    if (n < N) { starts[n] = myStart; cntN[n] = v; }
    __syncthreads();
    lc[threadIdx.x] = myStart;
    __syncthreads();
    for (int e = threadIdx.x; e < ec; e += 256) {
        unsigned int pd = pairs[e0 + e];
        int p = atomicAdd(&lc[pd >> 24], 1);
        col[p] = (int)(pd & 0xFFFFFF);
    }
}

// ===========================================================================
// pack_w: bf16 hi/lo B-fragments for mfma_f32_16x16x32_bf16 (proven, r2).
// frag f = ks*8+cf: k = ks*32+(l>>4)*8+i, col = cf*16+(l&15);
// layout out[f*512 + l*8 + i]. k-map matches A-side load order.
// ===========================================================================
struct PackW {
    const float* Wa[4]; const float* Wb[4];
    short* oh[4]; short* ol[4];
    int K[4];
};

__global__ __launch_bounds__(256) void pack_w(PackW p) {
    const int c = blockIdx.y;
    const int K = p.K[c];
    const int t = blockIdx.x * 256 + threadIdx.x;   // t = f*64 + l
    if (t >= K * 16) return;
    const int f  = t >> 6, l = t & 63;
    const int ks = f >> 3, cf = f & 7;
    const int col = cf * 16 + (l & 15);
    const int kb  = ks * 32 + ((l >> 4) * 8);
    const float* s = (col < 64) ? (p.Wa[c] + col) : (p.Wb[c] + (col - 64));
    short* oh = p.oh[c] + (size_t)t * 8;
    short* ol = p.ol[c] + (size_t)t * 8;
    #pragma unroll
    for (int i = 0; i < 8; ++i) {
        float v = s[(kb + i) * 64];
        short h = f2bf(v);
        oh[i] = h;
        ol[i] = f2bf(v - bf2f(h));
    }
}

// ===========================================================================
// proj_mfma2<K,TX,TB> (r12): dual projection, 512-thread blocks (8 waves),
// 256 rows/block, 32 rows/wave (2 A-frags).
//
// r11 post-mortem: 32 rows/wave at 2 waves/SIMD (64KB LDS, 256-thr blocks)
// stayed at ~1.8 TB/s — every lean variant has been occupancy-capped at
// 2 waves/SIMD; the only high-occupancy variant ever tested (r3, 27%) was
// the instruction-bloated one. fillBuffer in the same trace hits 6.5 TB/s
// at 8 waves/CU -> memory system is not the cap. r12 tests lean+occupancy:
// 512 threads share the 64KB W-stage -> 16 waves/CU = 4 waves/SIMD, double
// the in-flight load batches; W-staging L2 traffic halves.
// Epilogue: four 64-row rounds through the W-reuse LDS buffer.
// A-frag: lane l = row (l&15), k = ks*32+(l>>4)*8+i  (matches pack_w)
// C/D   : col = cf*16+(l&15), row = rf*16+lg*4+q     [HW-verified m89, r2]
// ===========================================================================
template<typename TX, typename TB> struct ProjJobT {
    const TX* x; const short* WH; const short* WL;
    _Float16* Pa; TB* Pb; int N;
};

static constexpr int PA_LD = 72;   // fp16 row pad (+16B) vs 64
static constexpr int PB_LD = 68;   // fp32 row pad (+16B) vs 64

template<int K, typename TX, typename TB>
__global__ __launch_bounds__(512) void proj_mfma2(
    ProjJobT<TX, TB> a, ProjJobT<TX, TB> b, int blocksA)
{
    constexpr int NKS = K / 32;
    // epilogue chunk = 64 rows: Pa fp16 [64][PA_LD] + Pb (f16 [64][PA_LD] |
    // f32 [64][PB_LD]) — expressed in shorts:
    constexpr int EPIL  = 64 * PA_LD + (sizeof(TB) == 2 ? 64 * PA_LD : 64 * PB_LD * 2);
    constexpr int LDSSH = (2 * K * 128 > EPIL) ? 2 * K * 128 : EPIL;
    __shared__ short sWbuf[LDSSH];
    short* sWH = sWbuf;
    short* sWL = sWbuf + K * 128;

    const bool isA = (int)blockIdx.x < blocksA;
    const ProjJobT<TX, TB> j = isA ? a : b;
    const int bid = isA ? blockIdx.x : blockIdx.x - blocksA;

    const int tid = threadIdx.x;
    const int l   = tid & 63;
    const int w   = tid >> 6;              // wave 0..7
    const int lr  = l & 15;
    const int lg  = l >> 4;
    const int r0  = bid * 256 + w * 32;    // wave owns rows [r0, r0+32)

    // ---- stage packed W (hi+lo) into LDS, coalesced 16B chunks ----
    for (int t = tid; t < K * 16; t += 512) {
        *(bf16x8*)(sWH + t * 8) = *(const bf16x8*)(j.WH + t * 8);
        *(bf16x8*)(sWL + t * 8) = *(const bf16x8*)(j.WL + t * 8);
    }

    // ---- x-loads for both row-fragments ----
    float vv[2][NKS][8];
    #pragma unroll
    for (int rf = 0; rf < 2; ++rf) {
        const int row = r0 + rf * 16 + lr;
        const bool ok = row < j.N;
        #pragma unroll
        for (int ks = 0; ks < NKS; ++ks) {
            if constexpr (sizeof(TX) == 4) {
                const float* xp = (const float*)j.x + (long long)row * K + lg * 8;
                float4 u0 = ok ? *(const float4*)(xp + ks * 32)     : make_float4(0.f,0.f,0.f,0.f);
                float4 u1 = ok ? *(const float4*)(xp + ks * 32 + 4) : make_float4(0.f,0.f,0.f,0.f);
                vv[rf][ks][0]=u0.x; vv[rf][ks][1]=u0.y; vv[rf][ks][2]=u0.z; vv[rf][ks][3]=u0.w;
                vv[rf][ks][4]=u1.x; vv[rf][ks][5]=u1.y; vv[rf][ks][6]=u1.z; vv[rf][ks][7]=u1.w;
            } else {
                const _Float16* xp = (const _Float16*)j.x + (long long)row * K + lg * 8;
                if (ok) {
                    half8 h = *(const half8*)(xp + ks * 32);
                    #pragma unroll
                    for (int i = 0; i < 8; ++i) vv[rf][ks][i] = (float)h[i];
                } else {
                    #pragma unroll
                    for (int i = 0; i < 8; ++i) vv[rf][ks][i] = 0.f;
                }
            }
        }
    }
    __syncthreads();

    f32x4 acc[2][8];
    #pragma unroll
    for (int rf = 0; rf < 2; ++rf)
        #pragma unroll
        for (int c = 0; c < 8; ++c) acc[rf][c] = (f32x4){0.f, 0.f, 0.f, 0.f};

    #pragma unroll
    for (int ks = 0; ks < NKS; ++ks) {
        bf16x8 ah[2], al[2];
        #pragma unroll
        for (int rf = 0; rf < 2; ++rf)
            #pragma unroll
            for (int i = 0; i < 8; ++i) {
                short h = f2bf(vv[rf][ks][i]);
                ah[rf][i] = h;
                al[rf][i] = f2bf(vv[rf][ks][i] - bf2f(h));
            }
        const short* wb = sWH + (ks * 8) * 512 + l * 8;
        const short* lb = sWL + (ks * 8) * 512 + l * 8;
        #pragma unroll
        for (int cf = 0; cf < 8; ++cf) {
            const bf16x8 bh = *(const bf16x8*)(wb + cf * 512);
            const bf16x8 bl = *(const bf16x8*)(lb + cf * 512);
            #pragma unroll
            for (int rf = 0; rf < 2; ++rf) {
                acc[rf][cf] = __builtin_amdgcn_mfma_f32_16x16x32_bf16(ah[rf], bh, acc[rf][cf], 0, 0, 0);
                acc[rf][cf] = __builtin_amdgcn_mfma_f32_16x16x32_bf16(ah[rf], bl, acc[rf][cf], 0, 0, 0);
                acc[rf][cf] = __builtin_amdgcn_mfma_f32_16x16x32_bf16(al[rf], bh, acc[rf][cf], 0, 0, 0);
            }
        }
    }

    // ---- epilogue: four 64-row rounds through the W-reuse buffer ----
    __syncthreads();   // all W ds_reads drained; safe to overwrite sWbuf
    _Float16* sPa  = (_Float16*)sWbuf;                   // [64][PA_LD]
    _Float16* sPbH = (_Float16*)(sWbuf + 64 * PA_LD);
    float*    sPbF = (float*)(sWbuf + 64 * PA_LD);

    #pragma unroll
    for (int rnd = 0; rnd < 4; ++rnd) {
        if ((w >> 1) == rnd) {
            const int lw = w & 1;                        // 0/1 within round
            #pragma unroll
            for (int rf = 0; rf < 2; ++rf)
                #pragma unroll
                for (int q = 0; q < 4; ++q) {
                    const int r = lw * 32 + rf * 16 + lg * 4 + q;  // 0..63
                    #pragma unroll
                    for (int cf = 0; cf < 8; ++cf) {
                        const float v = acc[rf][cf][q];
                        if (cf < 4) sPa[r * PA_LD + cf * 16 + lr] = (_Float16)v;
                        else if constexpr (sizeof(TB) == 2)
                            sPbH[r * PA_LD + (cf - 4) * 16 + lr] = (_Float16)v;
                        else
                            sPbF[r * PB_LD + (cf - 4) * 16 + lr] = v;
                    }
                }
        }
        __syncthreads();
        const int g0 = bid * 256 + rnd * 64;
        for (int c = tid; c < 512; c += 512) {
            const int r = c >> 3, cc = (c & 7) * 8;
            const int gr = g0 + r;
            if (gr < j.N)
                *(half8*)(j.Pa + (size_t)gr * 64 + cc) = *(half8*)(sPa + r * PA_LD + cc);
        }
        if constexpr (sizeof(TB) == 2) {
            for (int c = tid; c < 512; c += 512) {
                const int r = c >> 3, cc = (c & 7) * 8;
                const int gr = g0 + r;
                if (gr < j.N)
                    *(half8*)((_Float16*)j.Pb + (size_t)gr * 64 + cc) =
                        *(half8*)(sPbH + r * PA_LD + cc);
            }
        } else {
            for (int c = tid; c < 1024; c += 512) {
                const int r = c >> 4, cc = (c & 15) * 4;
                const int gr = g0 + r;
                if (gr < j.N)
                    *(float4*)((float*)j.Pb + (size_t)gr * 64 + cc) =
                        *(float4*)(sPbF + r * PB_LD + cc);
            }
        }
        __syncthreads();
    }
}

// ===========================================================================
// gather2<TO>: merged mean-aggregate, two jobs per dispatch (proven r4/r6/r8).
//   out[n,:] += mean_{e in CSR(n)} P[col[e],:] + bias[:]   (P fp16; out TO)
// ===========================================================================
template<typename TO> struct GatherJobT {
    const _Float16* P; const int* starts; const int* cnt; const int* col;
    const float* bias; TO* out; int N;
};

template<typename TO>
__global__ __launch_bounds__(256) void gather2(
    GatherJobT<TO> A, GatherJobT<TO> B, int blocksA)
{
    const bool isA = (int)blockIdx.x < blocksA;
    const GatherJobT<TO> g = isA ? A : B;
    const int bid = isA ? blockIdx.x : blockIdx.x - blocksA;

    const int lane = threadIdx.x & 63;
    const int wid  = (bid * 256 + threadIdx.x) >> 6;
    const int n    = wid * 4 + (lane >> 4);
    const int li   = lane & 15;
    if (n >= g.N) return;

    int e         = g.starts[n];
    const int deg = g.cnt[n];
    const int e1  = e + deg;

    float4 acc = make_float4(0.f, 0.f, 0.f, 0.f);
    while (e + 4 <= e1) {
        const int s0 = g.col[e], s1 = g.col[e + 1], s2 = g.col[e + 2], s3 = g.col[e + 3];
        const half4 v0 = *(const half4*)(g.P + (size_t)s0 * 64 + li * 4);
        const half4 v1 = *(const half4*)(g.P + (size_t)s1 * 64 + li * 4);
        const half4 v2 = *(const half4*)(g.P + (size_t)s2 * 64 + li * 4);
        const half4 v3 = *(const half4*)(g.P + (size_t)s3 * 64 + li * 4);
        acc.x += (float)v0[0] + (float)v1[0] + (float)v2[0] + (float)v3[0];
        acc.y += (float)v0[1] + (float)v1[1] + (float)v2[1] + (float)v3[1];
        acc.z += (float)v0[2] + (float)v1[2] + (float)v2[2] + (float)v3[2];
        acc.w += (float)v0[3] + (float)v1[3] + (float)v2[3] + (float)v3[3];
        e += 4;
    }
    while (e < e1) {
        const half4 v0 = *(const half4*)(g.P + (size_t)g.col[e] * 64 + li * 4);
        acc.x += (float)v0[0]; acc.y += (float)v0[1];
        acc.z += (float)v0[2]; acc.w += (float)v0[3];
        ++e;
    }
    const float inv = (deg > 0) ? 1.0f / (float)deg : 0.0f;
    const int c0 = li * 4;
    const float4 b4 = *(const float4*)&g.bias[c0];
    if constexpr (sizeof(TO) == 2) {
        _Float16* op = (_Float16*)g.out + (size_t)n * 64 + c0;
        half4 cur = *(half4*)op;
        cur[0] = (_Float16)((float)cur[0] + acc.x * inv + b4.x);
        cur[1] = (_Float16)((float)cur[1] + acc.y * inv + b4.y);
        cur[2] = (_Float16)((float)cur[2] + acc.z * inv + b4.z);
        cur[3] = (_Float16)((float)cur[3] + acc.w * inv + b4.w);
        *(half4*)op = cur;
    } else {
        float* op = (float*)g.out + (size_t)n * 64 + c0;
        float4 cur = *(float4*)op;
        cur.x += acc.x * inv + b4.x;
        cur.y += acc.y * inv + b4.y;
        cur.z += acc.z * inv + b4.z;
        cur.w += acc.w * inv + b4.w;
        *(float4*)op = cur;
    }
}

extern "C" void kernel_launch(void* const* d_in, const int* in_sizes, int n_in,
                              void* d_out, int out_size, void* d_ws, size_t ws_size,
                              hipStream_t stream) {
    const float* x_d    = (const float*)d_in[0];
    const float* x_g    = (const float*)d_in[1];
    const int* src_dg   = (const int*)d_in[2];
    const int* dst_dg   = (const int*)d_in[3];
    const int* src_gd   = (const int*)d_in[4];
    const int* dst_gd   = (const int*)d_in[5];
    const float* Wl1_dg = (const float*)d_in[6];
    const float* bl1_dg = (const float*)d_in[7];
    const float* Wr1_dg = (const float*)d_in[8];
    const float* Wl1_gd = (const float*)d_in[9];
    const float* bl1_gd = (const float*)d_in[10];
    const float* Wr1_gd = (const float*)d_in[11];
    const float* Wl2_dg = (const float*)d_in[12];
    const float* bl2_dg = (const float*)d_in[13];
    const float* Wr2_dg = (const float*)d_in[14];
    const float* Wl2_gd = (const float*)d_in[15];
    const float* bl2_gd = (const float*)d_in[16];
    const float* Wr2_gd = (const float*)d_in[17];

    const int nd = in_sizes[0] / DIN;   // 50000
    const int ng = in_sizes[1] / DIN;   // 100000
    const int ne = in_sizes[2];         // 600000

    // ---- workspace ----
    _Float16* P_d = (_Float16*)d_ws;                     // [nd,64] fp16 msg
    _Float16* P_g = P_d + (size_t)nd * HID;              // [ng,64]
    _Float16* d1h = P_g + (size_t)ng * HID;              // [nd,64] fp16 d1
    _Float16* g1h = d1h + (size_t)nd * HID;              // [ng,64] fp16 g1
    int* startsG = (int*)(g1h + (size_t)ng * HID);       // [ng]
    int* startsD = startsG + ng;                         // [nd]
    int* cntG    = startsD + nd;                         // [ng]
    int* cntD    = cntG + ng;                            // [nd]
    int* colG    = cntD + nd;                            // [ne]
    int* colD    = colG + ne;                            // [ne]
    int* binCnt  = colD + ne;                            // [1024]
    int* binBase = binCnt + 1024;                        // [1024]
    int* binCur  = binBase + 1024;                       // [1024]
    unsigned int* pairs = (unsigned int*)(binCur + 1024);// [2*ne] packed

    uintptr_t wp = (uintptr_t)(pairs + 2 * (size_t)ne);
    wp = (wp + 63) & ~(uintptr_t)63;
    short* wh0 = (short*)wp;        // K=128: 32 frags * 512
    short* wl0 = wh0 + 16384;
    short* wh1 = wl0 + 16384;
    short* wl1 = wh1 + 16384;
    short* wh2 = wl1 + 16384;       // K=64: 16 frags * 512
    short* wl2 = wh2 + 8192;
    short* wh3 = wl2 + 8192;
    short* wl3 = wh3 + 8192;

    float* out  = (float*)d_out;
    float* outD = out;                             // [nd,64] final d2
    float* outG = out + (size_t)nd * HID;          // [ng,64] final g2

    const int gBH = (ne + CHUNK - 1) / CHUNK;
    const int nbG = (ng + 255) >> 8;
    const int nbD = (nd + 255) >> 8;
    const int nbT = nbG + nbD;
    const int gM_g = (ng + 255) / 256;             // 391 tiles of 256 rows
    const int gM_d = (nd + 255) / 256;             // 196
    const int gG_g = (ng + 15) / 16;
    const int gG_d = (nd + 15) / 16;

    // ---- weight packing (once, tiny) ----
    PackW pw;
    pw.Wa[0] = Wl1_dg; pw.Wb[0] = Wr1_gd; pw.oh[0] = wh0; pw.ol[0] = wl0; pw.K[0] = 128;
    pw.Wa[1] = Wl1_gd; pw.Wb[1] = Wr1_dg; pw.oh[1] = wh1; pw.ol[1] = wl1; pw.K[1] = 128;
    pw.Wa[2] = Wl2_gd; pw.Wb[2] = Wr2_dg; pw.oh[2] = wh2; pw.ol[2] = wl2; pw.K[2] = 64;
    pw.Wa[3] = Wl2_dg; pw.Wb[3] = Wr2_gd; pw.oh[3] = wh3; pw.ol[3] = wl3; pw.K[3] = 64;
    pack_w<<<dim3(8, 4), 256, 0, stream>>>(pw);

    hipMemsetAsync(binCnt, 0, 1024 * sizeof(int), stream);

    // ---- CSR build: 4 dispatches, bin-local traffic ----
    binhist_kernel<<<2 * gBH, 256, 0, stream>>>(dst_dg, dst_gd, binCnt, ne, gBH, nbG, nbT);
    binscan_kernel<<<1, 1024, 0, stream>>>(binCnt, binBase, binCur, nbT);
    binplaceA_kernel<<<2 * gBH, 256, 0, stream>>>(src_dg, dst_dg, src_gd, dst_gd,
                                                  binCur, pairs, ne, gBH, nbG, nbT);
    binplaceB_kernel<<<nbT, 256, 0, stream>>>(pairs, binBase, binCnt,
                                              startsG, cntG, colG, ng,
                                              startsD, cntD, colD, nd, nbG, ne);

    // ---- layer 1: dual projections (K=128, f32 in, f16 self out) ----
    ProjJobT<float, _Float16> p1a = { x_d, wh0, wl0, P_d, d1h, nd };
    ProjJobT<float, _Float16> p1b = { x_g, wh1, wl1, P_g, g1h, ng };
    proj_mfma2<DIN, float, _Float16><<<gM_d + gM_g, 512, 0, stream>>>(p1a, p1b, gM_d);

    GatherJobT<_Float16> ga1 = { P_d, startsG, cntG, colG, bl1_dg, g1h, ng };  // g1
    GatherJobT<_Float16> gb1 = { P_g, startsD, cntD, colD, bl1_gd, d1h, nd };  // d1
    gather2<_Float16><<<gG_g + gG_d, 256, 0, stream>>>(ga1, gb1, gG_g);

    // ---- layer 2: dual projections (K=64, f16 in, f32 self -> final out) ----
    ProjJobT<_Float16, float> p2a = { g1h, wh2, wl2, P_g, outG, ng };  // msg d2 + self g2
    ProjJobT<_Float16, float> p2b = { d1h, wh3, wl3, P_d, outD, nd }; // msg g2 + self d2
    proj_mfma2<HID, _Float16, float><<<gM_g + gM_d, 512, 0, stream>>>(p2a, p2b, gM_g);

    GatherJobT<float> ga2 = { P_g, startsD, cntD, colD, bl2_gd, outD, nd };  // d2
    GatherJobT<float> gb2 = { P_d, startsG, cntG, colG, bl2_dg, outG, ng };  // g2
    gather2<float><<<gG_d + gG_g, 256, 0, stream>>>(ga2, gb2, gG_d);
}

// Round 13
// 312.340 us; speedup vs baseline: 1.0413x; 1.0413x over previous
//
#include <hip/hip_runtime.h>

static constexpr int DIN = 128;
static constexpr int HID = 64;
static constexpr int BIN_SHIFT = 8;    // 256 nodes per bin
static constexpr int CHUNK = 1024;     // r9 (neutral, kept)

typedef short bf16x8 __attribute__((ext_vector_type(8)));
typedef float f32x4  __attribute__((ext_vector_type(4)));
typedef _Float16 half4 __attribute__((ext_vector_type(4)));
typedef _Float16 half8 __attribute__((ext_vector_type(8)));

// bf16 helpers (manual RNE, no header dependence)
__device__ __forceinline__ short f2bf(float f) {
    unsigned u = __float_as_uint(f);
    unsigned r = (u + 0x7fff + ((u >> 16) & 1)) >> 16;
    return (short)r;
}
__device__ __forceinline__ float bf2f(short s) {
    return __uint_as_float(((unsigned)(unsigned short)s) << 16);
}

// ===========================================================================
// Two-level CSR build (proven r6/r8): bins of 256 nodes localize all scatter.
// pairs packed as (dstLocal<<24)|src (src < 2^17, dstLocal 8b).
// ===========================================================================
__global__ __launch_bounds__(256) void binhist_kernel(
    const int* __restrict__ dstA, const int* __restrict__ dstB,
    int* __restrict__ binCnt, int nE, int gA, int nbA, int nbT)
{
    __shared__ int c[1024];
    for (int b = threadIdx.x; b < 1024; b += 256) c[b] = 0;
    __syncthreads();
    const int blk = blockIdx.x;
    const bool isA = blk < gA;
    const int* dst = isA ? dstA : dstB;
    const int off  = isA ? 0 : nbA;
    const int i0   = (isA ? blk : blk - gA) * CHUNK;
    #pragma unroll 4
    for (int k = 0; k < CHUNK / 256; ++k) {
        int i = i0 + k * 256 + threadIdx.x;
        if (i < nE) atomicAdd(&c[off + (dst[i] >> BIN_SHIFT)], 1);
    }
    __syncthreads();
    for (int b = threadIdx.x; b < nbT; b += 256) {
        int v = c[b];
        if (v) atomicAdd(&binCnt[b], v);
    }
}

__global__ __launch_bounds__(1024) void binscan_kernel(
    const int* __restrict__ binCnt, int* __restrict__ binBase,
    int* __restrict__ binCur, int nbT)
{
    __shared__ int s[1024];
    int v = (threadIdx.x < nbT) ? binCnt[threadIdx.x] : 0;
    s[threadIdx.x] = v;
    __syncthreads();
    for (int o = 1; o < 1024; o <<= 1) {
        int t = (threadIdx.x >= o) ? s[threadIdx.x - o] : 0;
        __syncthreads();
        s[threadIdx.x] += t;
        __syncthreads();
    }
    if (threadIdx.x < nbT) {
        binBase[threadIdx.x] = s[threadIdx.x] - v;
        binCur[threadIdx.x]  = s[threadIdx.x] - v;
    }
}

__global__ __launch_bounds__(256) void binplaceA_kernel(
    const int* __restrict__ srcA, const int* __restrict__ dstA,
    const int* __restrict__ srcB, const int* __restrict__ dstB,
    int* __restrict__ binCur, unsigned int* __restrict__ pairs,
    int nE, int gA, int nbA, int nbT)
{
    __shared__ int cnt[1024];
    __shared__ int base[1024];
    for (int b = threadIdx.x; b < 1024; b += 256) cnt[b] = 0;
    __syncthreads();
    const int blk = blockIdx.x;
    const bool isA = blk < gA;
    const int* src = isA ? srcA : srcB;
    const int* dst = isA ? dstA : dstB;
    const int off  = isA ? 0 : nbA;
    const int i0   = (isA ? blk : blk - gA) * CHUNK;
    #pragma unroll 4
    for (int k = 0; k < CHUNK / 256; ++k) {
        int i = i0 + k * 256 + threadIdx.x;
        if (i < nE) atomicAdd(&cnt[off + (dst[i] >> BIN_SHIFT)], 1);
    }
    __syncthreads();
    for (int b = threadIdx.x; b < nbT; b += 256) {
        int v = cnt[b];
        base[b] = v ? atomicAdd(&binCur[b], v) : 0;
        cnt[b] = 0;
    }
    __syncthreads();
    #pragma unroll 4
    for (int k = 0; k < CHUNK / 256; ++k) {
        int i = i0 + k * 256 + threadIdx.x;
        if (i < nE) {
            int d  = dst[i];
            int bn = off + (d >> BIN_SHIFT);
            int p  = base[bn] + atomicAdd(&cnt[bn], 1);
            pairs[p] = ((unsigned)(d & 255) << 24) | (unsigned)src[i];
        }
    }
}

__global__ __launch_bounds__(256) void binplaceB_kernel(
    const unsigned int* __restrict__ pairs,
    const int* __restrict__ binBase, const int* __restrict__ binCnt,
    int* __restrict__ startsA, int* __restrict__ cntA, int* __restrict__ colA, int NA,
    int* __restrict__ startsB, int* __restrict__ cntB, int* __restrict__ colB, int NB,
    int nbA, int nE)
{
    __shared__ int lc[256];
    __shared__ int pr[256];
    const int b    = blockIdx.x;
    const bool isA = b < nbA;
    int* starts = isA ? startsA : startsB;
    int* cntN   = isA ? cntA : cntB;
    int* col    = isA ? colA : colB;
    const int N     = isA ? NA : NB;
    const int node0 = (isA ? b : b - nbA) << BIN_SHIFT;
    const int e0 = binBase[b];
    const int ec = binCnt[b];
    const int colBase = isA ? e0 : e0 - nE;

    lc[threadIdx.x] = 0;
    __syncthreads();
    for (int e = threadIdx.x; e < ec; e += 256)
        atomicAdd(&lc[pairs[e0 + e] >> 24], 1);
    __syncthreads();
    const int v = lc[threadIdx.x];
    pr[threadIdx.x] = v;
    __syncthreads();
    for (int o = 1; o < 256; o <<= 1) {
        int t = (threadIdx.x >= o) ? pr[threadIdx.x - o] : 0;
        __syncthreads();
        pr[threadIdx.x] += t;
        __syncthreads();
    }
    const int myStart = colBase + pr[threadIdx.x] - v;
    const int n = node0 + threadIdx.x;
    if (n < N) { starts[n] = myStart; cntN[n] = v; }
    __syncthreads();
    lc[threadIdx.x] = myStart;
    __syncthreads();
    for (int e = threadIdx.x; e < ec; e += 256) {
        unsigned int pd = pairs[e0 + e];
        int p = atomicAdd(&lc[pd >> 24], 1);
        col[p] = (int)(pd & 0xFFFFFF);
    }
}

// ===========================================================================
// pack_w: bf16 hi/lo B-fragments for mfma_f32_16x16x32_bf16 (proven, r2).
// frag f = ks*8+cf: k = ks*32+(l>>4)*8+i, col = cf*16+(l&15);
// layout out[f*512 + l*8 + i]. k-map matches A-side load order.
// ===========================================================================
struct PackW {
    const float* Wa[4]; const float* Wb[4];
    short* oh[4]; short* ol[4];
    int K[4];
};

__global__ __launch_bounds__(256) void pack_w(PackW p) {
    const int c = blockIdx.y;
    const int K = p.K[c];
    const int t = blockIdx.x * 256 + threadIdx.x;   // t = f*64 + l
    if (t >= K * 16) return;
    const int f  = t >> 6, l = t & 63;
    const int ks = f >> 3, cf = f & 7;
    const int col = cf * 16 + (l & 15);
    const int kb  = ks * 32 + ((l >> 4) * 8);
    const float* s = (col < 64) ? (p.Wa[c] + col) : (p.Wb[c] + (col - 64));
    short* oh = p.oh[c] + (size_t)t * 8;
    short* ol = p.ol[c] + (size_t)t * 8;
    #pragma unroll
    for (int i = 0; i < 8; ++i) {
        float v = s[(kb + i) * 64];
        short h = f2bf(v);
        oh[i] = h;
        ol[i] = f2bf(v - bf2f(h));
    }
}

// ===========================================================================
// proj_mfma2<K,TX,TB> (r11 BEST, restored after r12 regression):
// dual projection, 32 rows/WAVE (2 A-frags), 256-thread blocks, 128 rows.
//
// CLOSED per r12: configurations spanning occupancy 12-33%, VMEM/wave
// 104->14, tiles 16/32 rows, blocks 256/512 all converge to ~1.5-2.1 TB/s
// for this mixed strided-R/W shape — platform rate wall, not code.
// A-frag: lane l = row (l&15), k = ks*32+(l>>4)*8+i  (matches pack_w)
// C/D   : col = cf*16+(l&15), row = rf*16+lg*4+q     [HW-verified m89, r2]
// ===========================================================================
template<typename TX, typename TB> struct ProjJobT {
    const TX* x; const short* WH; const short* WL;
    _Float16* Pa; TB* Pb; int N;
};

static constexpr int PA_LD = 72;   // fp16 row pad (+16B) vs 64
static constexpr int PB_LD = 68;   // fp32 row pad (+16B) vs 64

template<int K, typename TX, typename TB>
__global__ __launch_bounds__(256) void proj_mfma2(
    ProjJobT<TX, TB> a, ProjJobT<TX, TB> b, int blocksA)
{
    constexpr int NKS = K / 32;
    // epilogue chunk = 64 rows: Pa fp16 [64][PA_LD] + Pb (f16 [64][PA_LD] |
    // f32 [64][PB_LD]) — expressed in shorts:
    constexpr int EPIL  = 64 * PA_LD + (sizeof(TB) == 2 ? 64 * PA_LD : 64 * PB_LD * 2);
    constexpr int LDSSH = (2 * K * 128 > EPIL) ? 2 * K * 128 : EPIL;
    __shared__ short sWbuf[LDSSH];
    short* sWH = sWbuf;
    short* sWL = sWbuf + K * 128;

    const bool isA = (int)blockIdx.x < blocksA;
    const ProjJobT<TX, TB> j = isA ? a : b;
    const int bid = isA ? blockIdx.x : blockIdx.x - blocksA;

    const int tid = threadIdx.x;
    const int l   = tid & 63;
    const int w   = tid >> 6;
    const int lr  = l & 15;
    const int lg  = l >> 4;
    const int r0  = bid * 128 + w * 32;    // wave owns rows [r0, r0+32)

    // ---- stage packed W (hi+lo) into LDS, coalesced 16B chunks ----
    for (int t = tid; t < K * 16; t += 256) {
        *(bf16x8*)(sWH + t * 8) = *(const bf16x8*)(j.WH + t * 8);
        *(bf16x8*)(sWL + t * 8) = *(const bf16x8*)(j.WL + t * 8);
    }

    // ---- x-loads for both row-fragments ----
    float vv[2][NKS][8];
    #pragma unroll
    for (int rf = 0; rf < 2; ++rf) {
        const int row = r0 + rf * 16 + lr;
        const bool ok = row < j.N;
        #pragma unroll
        for (int ks = 0; ks < NKS; ++ks) {
            if constexpr (sizeof(TX) == 4) {
                const float* xp = (const float*)j.x + (long long)row * K + lg * 8;
                float4 u0 = ok ? *(const float4*)(xp + ks * 32)     : make_float4(0.f,0.f,0.f,0.f);
                float4 u1 = ok ? *(const float4*)(xp + ks * 32 + 4) : make_float4(0.f,0.f,0.f,0.f);
                vv[rf][ks][0]=u0.x; vv[rf][ks][1]=u0.y; vv[rf][ks][2]=u0.z; vv[rf][ks][3]=u0.w;
                vv[rf][ks][4]=u1.x; vv[rf][ks][5]=u1.y; vv[rf][ks][6]=u1.z; vv[rf][ks][7]=u1.w;
            } else {
                const _Float16* xp = (const _Float16*)j.x + (long long)row * K + lg * 8;
                if (ok) {
                    half8 h = *(const half8*)(xp + ks * 32);
                    #pragma unroll
                    for (int i = 0; i < 8; ++i) vv[rf][ks][i] = (float)h[i];
                } else {
                    #pragma unroll
                    for (int i = 0; i < 8; ++i) vv[rf][ks][i] = 0.f;
                }
            }
        }
    }
    __syncthreads();

    f32x4 acc[2][8];
    #pragma unroll
    for (int rf = 0; rf < 2; ++rf)
        #pragma unroll
        for (int c = 0; c < 8; ++c) acc[rf][c] = (f32x4){0.f, 0.f, 0.f, 0.f};

    #pragma unroll
    for (int ks = 0; ks < NKS; ++ks) {
        bf16x8 ah[2], al[2];
        #pragma unroll
        for (int rf = 0; rf < 2; ++rf)
            #pragma unroll
            for (int i = 0; i < 8; ++i) {
                short h = f2bf(vv[rf][ks][i]);
                ah[rf][i] = h;
                al[rf][i] = f2bf(vv[rf][ks][i] - bf2f(h));
            }
        const short* wb = sWH + (ks * 8) * 512 + l * 8;
        const short* lb = sWL + (ks * 8) * 512 + l * 8;
        #pragma unroll
        for (int cf = 0; cf < 8; ++cf) {
            const bf16x8 bh = *(const bf16x8*)(wb + cf * 512);
            const bf16x8 bl = *(const bf16x8*)(lb + cf * 512);
            #pragma unroll
            for (int rf = 0; rf < 2; ++rf) {
                acc[rf][cf] = __builtin_amdgcn_mfma_f32_16x16x32_bf16(ah[rf], bh, acc[rf][cf], 0, 0, 0);
                acc[rf][cf] = __builtin_amdgcn_mfma_f32_16x16x32_bf16(ah[rf], bl, acc[rf][cf], 0, 0, 0);
                acc[rf][cf] = __builtin_amdgcn_mfma_f32_16x16x32_bf16(al[rf], bh, acc[rf][cf], 0, 0, 0);
            }
        }
    }

    // ---- epilogue: two 64-row rounds through the W-reuse buffer ----
    __syncthreads();   // all W ds_reads drained; safe to overwrite sWbuf
    _Float16* sPa  = (_Float16*)sWbuf;                   // [64][PA_LD]
    _Float16* sPbH = (_Float16*)(sWbuf + 64 * PA_LD);
    float*    sPbF = (float*)(sWbuf + 64 * PA_LD);

    #pragma unroll
    for (int rnd = 0; rnd < 2; ++rnd) {
        if ((w >> 1) == rnd) {
            const int lw = w & 1;                        // 0/1 within round
            #pragma unroll
            for (int rf = 0; rf < 2; ++rf)
                #pragma unroll
                for (int q = 0; q < 4; ++q) {
                    const int r = lw * 32 + rf * 16 + lg * 4 + q;  // 0..63
                    #pragma unroll
                    for (int cf = 0; cf < 8; ++cf) {
                        const float v = acc[rf][cf][q];
                        if (cf < 4) sPa[r * PA_LD + cf * 16 + lr] = (_Float16)v;
                        else if constexpr (sizeof(TB) == 2)
                            sPbH[r * PA_LD + (cf - 4) * 16 + lr] = (_Float16)v;
                        else
                            sPbF[r * PB_LD + (cf - 4) * 16 + lr] = v;
                    }
                }
        }
        __syncthreads();
        const int g0 = bid * 128 + rnd * 64;
        for (int c = tid; c < 512; c += 256) {
            const int r = c >> 3, cc = (c & 7) * 8;
            const int gr = g0 + r;
            if (gr < j.N)
                *(half8*)(j.Pa + (size_t)gr * 64 + cc) = *(half8*)(sPa + r * PA_LD + cc);
        }
        if constexpr (sizeof(TB) == 2) {
            for (int c = tid; c < 512; c += 256) {
                const int r = c >> 3, cc = (c & 7) * 8;
                const int gr = g0 + r;
                if (gr < j.N)
                    *(half8*)((_Float16*)j.Pb + (size_t)gr * 64 + cc) =
                        *(half8*)(sPbH + r * PA_LD + cc);
            }
        } else {
            for (int c = tid; c < 1024; c += 256) {
                const int r = c >> 4, cc = (c & 15) * 4;
                const int gr = g0 + r;
                if (gr < j.N)
                    *(float4*)((float*)j.Pb + (size_t)gr * 64 + cc) =
                        *(float4*)(sPbF + r * PB_LD + cc);
            }
        }
        __syncthreads();
    }
}

// ===========================================================================
// gather2<TO>: merged mean-aggregate, two jobs per dispatch (proven r4/r6/r8).
//   out[n,:] += mean_{e in CSR(n)} P[col[e],:] + bias[:]   (P fp16; out TO)
// ===========================================================================
template<typename TO> struct GatherJobT {
    const _Float16* P; const int* starts; const int* cnt; const int* col;
    const float* bias; TO* out; int N;
};

template<typename TO>
__global__ __launch_bounds__(256) void gather2(
    GatherJobT<TO> A, GatherJobT<TO> B, int blocksA)
{
    const bool isA = (int)blockIdx.x < blocksA;
    const GatherJobT<TO> g = isA ? A : B;
    const int bid = isA ? blockIdx.x : blockIdx.x - blocksA;

    const int lane = threadIdx.x & 63;
    const int wid  = (bid * 256 + threadIdx.x) >> 6;
    const int n    = wid * 4 + (lane >> 4);
    const int li   = lane & 15;
    if (n >= g.N) return;

    int e         = g.starts[n];
    const int deg = g.cnt[n];
    const int e1  = e + deg;

    float4 acc = make_float4(0.f, 0.f, 0.f, 0.f);
    while (e + 4 <= e1) {
        const int s0 = g.col[e], s1 = g.col[e + 1], s2 = g.col[e + 2], s3 = g.col[e + 3];
        const half4 v0 = *(const half4*)(g.P + (size_t)s0 * 64 + li * 4);
        const half4 v1 = *(const half4*)(g.P + (size_t)s1 * 64 + li * 4);
        const half4 v2 = *(const half4*)(g.P + (size_t)s2 * 64 + li * 4);
        const half4 v3 = *(const half4*)(g.P + (size_t)s3 * 64 + li * 4);
        acc.x += (float)v0[0] + (float)v1[0] + (float)v2[0] + (float)v3[0];
        acc.y += (float)v0[1] + (float)v1[1] + (float)v2[1] + (float)v3[1];
        acc.z += (float)v0[2] + (float)v1[2] + (float)v2[2] + (float)v3[2];
        acc.w += (float)v0[3] + (float)v1[3] + (float)v2[3] + (float)v3[3];
        e += 4;
    }
    while (e < e1) {
        const half4 v0 = *(const half4*)(g.P + (size_t)g.col[e] * 64 + li * 4);
        acc.x += (float)v0[0]; acc.y += (float)v0[1];
        acc.z += (float)v0[2]; acc.w += (float)v0[3];
        ++e;
    }
    const float inv = (deg > 0) ? 1.0f / (float)deg : 0.0f;
    const int c0 = li * 4;
    const float4 b4 = *(const float4*)&g.bias[c0];
    if constexpr (sizeof(TO) == 2) {
        _Float16* op = (_Float16*)g.out + (size_t)n * 64 + c0;
        half4 cur = *(half4*)op;
        cur[0] = (_Float16)((float)cur[0] + acc.x * inv + b4.x);
        cur[1] = (_Float16)((float)cur[1] + acc.y * inv + b4.y);
        cur[2] = (_Float16)((float)cur[2] + acc.z * inv + b4.z);
        cur[3] = (_Float16)((float)cur[3] + acc.w * inv + b4.w);
        *(half4*)op = cur;
    } else {
        float* op = (float*)g.out + (size_t)n * 64 + c0;
        float4 cur = *(float4*)op;
        cur.x += acc.x * inv + b4.x;
        cur.y += acc.y * inv + b4.y;
        cur.z += acc.z * inv + b4.z;
        cur.w += acc.w * inv + b4.w;
        *(float4*)op = cur;
    }
}

extern "C" void kernel_launch(void* const* d_in, const int* in_sizes, int n_in,
                              void* d_out, int out_size, void* d_ws, size_t ws_size,
                              hipStream_t stream) {
    const float* x_d    = (const float*)d_in[0];
    const float* x_g    = (const float*)d_in[1];
    const int* src_dg   = (const int*)d_in[2];
    const int* dst_dg   = (const int*)d_in[3];
    const int* src_gd   = (const int*)d_in[4];
    const int* dst_gd   = (const int*)d_in[5];
    const float* Wl1_dg = (const float*)d_in[6];
    const float* bl1_dg = (const float*)d_in[7];
    const float* Wr1_dg = (const float*)d_in[8];
    const float* Wl1_gd = (const float*)d_in[9];
    const float* bl1_gd = (const float*)d_in[10];
    const float* Wr1_gd = (const float*)d_in[11];
    const float* Wl2_dg = (const float*)d_in[12];
    const float* bl2_dg = (const float*)d_in[13];
    const float* Wr2_dg = (const float*)d_in[14];
    const float* Wl2_gd = (const float*)d_in[15];
    const float* bl2_gd = (const float*)d_in[16];
    const float* Wr2_gd = (const float*)d_in[17];

    const int nd = in_sizes[0] / DIN;   // 50000
    const int ng = in_sizes[1] / DIN;   // 100000
    const int ne = in_sizes[2];         // 600000

    // ---- workspace ----
    _Float16* P_d = (_Float16*)d_ws;                     // [nd,64] fp16 msg
    _Float16* P_g = P_d + (size_t)nd * HID;              // [ng,64]
    _Float16* d1h = P_g + (size_t)ng * HID;              // [nd,64] fp16 d1
    _Float16* g1h = d1h + (size_t)nd * HID;              // [ng,64] fp16 g1
    int* startsG = (int*)(g1h + (size_t)ng * HID);       // [ng]
    int* startsD = startsG + ng;                         // [nd]
    int* cntG    = startsD + nd;                         // [ng]
    int* cntD    = cntG + ng;                            // [nd]
    int* colG    = cntD + nd;                            // [ne]
    int* colD    = colG + ne;                            // [ne]
    int* binCnt  = colD + ne;                            // [1024]
    int* binBase = binCnt + 1024;                        // [1024]
    int* binCur  = binBase + 1024;                       // [1024]
    unsigned int* pairs = (unsigned int*)(binCur + 1024);// [2*ne] packed

    uintptr_t wp = (uintptr_t)(pairs + 2 * (size_t)ne);
    wp = (wp + 63) & ~(uintptr_t)63;
    short* wh0 = (short*)wp;        // K=128: 32 frags * 512
    short* wl0 = wh0 + 16384;
    short* wh1 = wl0 + 16384;
    short* wl1 = wh1 + 16384;
    short* wh2 = wl1 + 16384;       // K=64: 16 frags * 512
    short* wl2 = wh2 + 8192;
    short* wh3 = wl2 + 8192;
    short* wl3 = wh3 + 8192;

    float* out  = (float*)d_out;
    float* outD = out;                             // [nd,64] final d2
    float* outG = out + (size_t)nd * HID;          // [ng,64] final g2

    const int gBH = (ne + CHUNK - 1) / CHUNK;
    const int nbG = (ng + 255) >> 8;
    const int nbD = (nd + 255) >> 8;
    const int nbT = nbG + nbD;
    const int gM_g = (ng + 127) / 128;             // 782 tiles of 128 rows
    const int gM_d = (nd + 127) / 128;             // 391
    const int gG_g = (ng + 15) / 16;
    const int gG_d = (nd + 15) / 16;

    // ---- weight packing (once, tiny) ----
    PackW pw;
    pw.Wa[0] = Wl1_dg; pw.Wb[0] = Wr1_gd; pw.oh[0] = wh0; pw.ol[0] = wl0; pw.K[0] = 128;
    pw.Wa[1] = Wl1_gd; pw.Wb[1] = Wr1_dg; pw.oh[1] = wh1; pw.ol[1] = wl1; pw.K[1] = 128;
    pw.Wa[2] = Wl2_gd; pw.Wb[2] = Wr2_dg; pw.oh[2] = wh2; pw.ol[2] = wl2; pw.K[2] = 64;
    pw.Wa[3] = Wl2_dg; pw.Wb[3] = Wr2_gd; pw.oh[3] = wh3; pw.ol[3] = wl3; pw.K[3] = 64;
    pack_w<<<dim3(8, 4), 256, 0, stream>>>(pw);

    hipMemsetAsync(binCnt, 0, 1024 * sizeof(int), stream);

    // ---- CSR build: 4 dispatches, bin-local traffic ----
    binhist_kernel<<<2 * gBH, 256, 0, stream>>>(dst_dg, dst_gd, binCnt, ne, gBH, nbG, nbT);
    binscan_kernel<<<1, 1024, 0, stream>>>(binCnt, binBase, binCur, nbT);
    binplaceA_kernel<<<2 * gBH, 256, 0, stream>>>(src_dg, dst_dg, src_gd, dst_gd,
                                                  binCur, pairs, ne, gBH, nbG, nbT);
    binplaceB_kernel<<<nbT, 256, 0, stream>>>(pairs, binBase, binCnt,
                                              startsG, cntG, colG, ng,
                                              startsD, cntD, colD, nd, nbG, ne);

    // ---- layer 1: dual projections (K=128, f32 in, f16 self out) ----
    ProjJobT<float, _Float16> p1a = { x_d, wh0, wl0, P_d, d1h, nd };
    ProjJobT<float, _Float16> p1b = { x_g, wh1, wl1, P_g, g1h, ng };
    proj_mfma2<DIN, float, _Float16><<<gM_d + gM_g, 256, 0, stream>>>(p1a, p1b, gM_d);

    GatherJobT<_Float16> ga1 = { P_d, startsG, cntG, colG, bl1_dg, g1h, ng };  // g1
    GatherJobT<_Float16> gb1 = { P_g, startsD, cntD, colD, bl1_gd, d1h, nd };  // d1
    gather2<_Float16><<<gG_g + gG_d, 256, 0, stream>>>(ga1, gb1, gG_g);

    // ---- layer 2: dual projections (K=64, f16 in, f32 self -> final out) ----
    ProjJobT<_Float16, float> p2a = { g1h, wh2, wl2, P_g, outG, ng };  // msg d2 + self g2
    ProjJobT<_Float16, float> p2b = { d1h, wh3, wl3, P_d, outD, nd }; // msg g2 + self d2
    proj_mfma2<HID, _Float16, float><<<gM_g + gM_d, 256, 0, stream>>>(p2a, p2b, gM_g);

    GatherJobT<float> ga2 = { P_g, startsD, cntD, colD, bl2_gd, outD, nd };  // d2
    GatherJobT<float> gb2 = { P_d, startsG, cntG, colG, bl2_dg, outG, ng };  // g2
    gather2<float><<<gG_d + gG_g, 256, 0, stream>>>(ga2, gb2, gG_d);
}